// Round 4
// baseline (93.022 us; speedup 1.0000x reference)
//
#include <hip/hip_runtime.h>

#define NTOK 2048

typedef __attribute__((ext_vector_type(8))) short s8v;
typedef __attribute__((ext_vector_type(4))) float f32x4;

__device__ inline unsigned short f2bf(float f) {
  unsigned u = __builtin_bit_cast(unsigned, f);
  u += 0x7FFFu + ((u >> 16) & 1u);
  return (unsigned short)(u >> 16);
}
__device__ inline unsigned fkey(float f) {
  unsigned u = __builtin_bit_cast(unsigned, f);
  return (u & 0x80000000u) ? ~u : (u | 0x80000000u);
}
__device__ inline float kdec(unsigned k) {
  unsigned u = (k & 0x80000000u) ? (k ^ 0x80000000u) : ~k;
  return __builtin_bit_cast(float, u);
}

// ---- Kernel 0: init the atomic min/max cells (graph-capture safe) ----
__global__ void gat_init(unsigned* gmaxk, unsigned* gmink) {
  int t = threadIdx.x;
  if (t < 8) { gmaxk[t] = 0u; gmink[t] = 0xFFFFFFFFu; }
}

// ---- Kernel A: Wh = h@W, f1/f2 = Wh@a1/a2, WhT = bf16(Wh)^T, f2 min/max ----
__global__ __launch_bounds__(256) void gat_pre(
    const float* __restrict__ h, const float* __restrict__ W,
    const float* __restrict__ a, unsigned short* __restrict__ WhT,
    float* __restrict__ f1, float* __restrict__ f2,
    unsigned* __restrict__ gmaxk, unsigned* __restrict__ gmink) {
  __shared__ float wL[128 * 64];            // 32 KB
  __shared__ float hL[16 * 128];            // 8 KB
  __shared__ unsigned short tL[64 * 16];    // 2 KB transpose buffer
  __shared__ float bmx[4], bmn[4];
  int t = threadIdx.x;
  {
    const float4* W4 = (const float4*)W;
    float4* wL4 = (float4*)wL;
#pragma unroll
    for (int k = 0; k < 8; ++k) wL4[t + 256 * k] = W4[t + 256 * k];
    const float4* h4 = (const float4*)(h + (size_t)blockIdx.x * 16 * 128);
    float4* hL4 = (float4*)hL;
#pragma unroll
    for (int k = 0; k < 2; ++k) hL4[t + 256 * k] = h4[t + 256 * k];
  }
  __syncthreads();
  int w = t >> 6, lane = t & 63;
  float acc[4] = {0.f, 0.f, 0.f, 0.f};
  for (int kc = 0; kc < 128; kc += 32) {
    float wreg[32];
#pragma unroll
    for (int kk = 0; kk < 32; ++kk) wreg[kk] = wL[(kc + kk) * 64 + lane];
#pragma unroll
    for (int r = 0; r < 4; ++r) {
      const float* hrow = &hL[(w * 4 + r) * 128 + kc];
#pragma unroll
      for (int kk = 0; kk < 32; kk += 4) {
        float4 hv = *(const float4*)(hrow + kk);
        acc[r] += hv.x * wreg[kk] + hv.y * wreg[kk + 1] +
                  hv.z * wreg[kk + 2] + hv.w * wreg[kk + 3];
      }
    }
  }
  float a1 = a[lane], a2 = a[lane + 64];
  int row0 = blockIdx.x * 16 + w * 4;
  float wmx = -3.4e38f, wmn = 3.4e38f;
#pragma unroll
  for (int r = 0; r < 4; ++r) {
    int row = row0 + r;
    float v1 = acc[r] * a1, v2 = acc[r] * a2;
#pragma unroll
    for (int s = 32; s; s >>= 1) {
      v1 += __shfl_xor(v1, s, 64);
      v2 += __shfl_xor(v2, s, 64);
    }
    if (lane == 0) { f1[row] = v1; f2[row] = v2; }
    wmx = fmaxf(wmx, v2);
    wmn = fminf(wmn, v2);
    tL[lane * 16 + w * 4 + r] = f2bf(acc[r]);
  }
  if (lane == 0) { bmx[w] = wmx; bmn[w] = wmn; }
  __syncthreads();
  int b = (blockIdx.x * 16) / NTOK;
  if (t == 0) {
    float mx = fmaxf(fmaxf(bmx[0], bmx[1]), fmaxf(bmx[2], bmx[3]));
    float mn = fminf(fminf(bmn[0], bmn[1]), fminf(bmn[2], bmn[3]));
    atomicMax(&gmaxk[b], fkey(mx));
    atomicMin(&gmink[b], fkey(mn));
  }
  // coalesced bf16 write of WhT[b][feat][tok]
  int tok0 = (blockIdx.x * 16) % NTOK;
  int feat = t >> 2, rl = (t & 3) * 4;
  uint2 v = *(const uint2*)&tL[feat * 16 + rl];
  *(uint2*)(WhT + ((size_t)b * 64 + feat) * NTOK + tok0 + rl) = v;
}

// ---- Kernel B: fused mask+softmax+PV. grid (128,8), 512 thr = 8 waves. ----
// Wave w: k-slice [w*256, w*256+256) for 16 rows, as 8 chunks of K=32.
// Lane (l15,lhi): A-frag row=l15, k = ch*32 + lhi*8 + j. Scores computed
// directly in fragment layout; safe upper-bound m[i] from per-batch f2
// min/max removes the row-max reduction entirely.
__global__ __launch_bounds__(512, 4) void gat_main(
    const int* __restrict__ adj, const unsigned short* __restrict__ WhT,
    const float* __restrict__ f1, const float* __restrict__ f2,
    const unsigned* __restrict__ gmaxk, const unsigned* __restrict__ gmink,
    float* __restrict__ out) {
  __shared__ float red[8 * 16 * 68];  // [wave][row][feat(pad 68)] ~34.8 KB
  __shared__ float sums[8 * 16];
  int t = threadIdx.x;
  int b = blockIdx.y;
  int i0 = blockIdx.x * 16;
  int w = t >> 6, lane = t & 63, l15 = lane & 15, lhi = lane >> 4;

  float f1v = f1[(size_t)b * NTOK + i0 + l15];
  float gmx = kdec(gmaxk[b]), gmn = kdec(gmink[b]);
  float mr = fmaxf(f1v * gmx, f1v * gmn);
  float m = fmaxf(mr, 0.01f * mr);  // leaky_relu(mr) >= all leaky(f1v*f2[j])

  const int* arow = adj + ((size_t)b * NTOK + i0 + l15) * NTOK;
  const float* f2p = f2 + (size_t)b * NTOK;
  const unsigned short* WhB = WhT + (size_t)b * 64 * NTOK;

  f32x4 ac0 = {0.f, 0.f, 0.f, 0.f}, ac1 = ac0, ac2 = ac0, ac3 = ac0;
  float ssum = 0.f;
  int kbase = w * 256 + lhi * 8;

#pragma unroll
  for (int ch = 0; ch < 8; ++ch) {
    int k = kbase + ch * 32;
    int4 aa0 = *(const int4*)(arow + k);
    int4 aa1 = *(const int4*)(arow + k + 4);
    float4 v0 = *(const float4*)(f2p + k);
    float4 v1 = *(const float4*)(f2p + k + 4);
    const unsigned short* bp = WhB + (size_t)l15 * NTOK + w * 256 + ch * 32 + lhi * 8;
    s8v bf0 = *(const s8v*)(bp);
    s8v bf1 = *(const s8v*)(bp + 16 * NTOK);
    s8v bf2 = *(const s8v*)(bp + 32 * NTOK);
    s8v bf3 = *(const s8v*)(bp + 48 * NTOK);

    float sv[8] = {f1v * v0.x, f1v * v0.y, f1v * v0.z, f1v * v0.w,
                   f1v * v1.x, f1v * v1.y, f1v * v1.z, f1v * v1.w};
    int am[8] = {aa0.x, aa0.y, aa0.z, aa0.w, aa1.x, aa1.y, aa1.z, aa1.w};
    s8v af;
#pragma unroll
    for (int q = 0; q < 8; ++q) {
      float s = sv[q];
      float lk = fmaxf(s, 0.01f * s);
      float pe = __expf(lk - m);
      float p = am[q] > 0 ? pe : 0.f;
      ssum += p;
      unsigned u = __builtin_bit_cast(unsigned, p) + 0x8000u;
      af[q] = (short)(u >> 16);
    }
    ac0 = __builtin_amdgcn_mfma_f32_16x16x32_bf16(af, bf0, ac0, 0, 0, 0);
    ac1 = __builtin_amdgcn_mfma_f32_16x16x32_bf16(af, bf1, ac1, 0, 0, 0);
    ac2 = __builtin_amdgcn_mfma_f32_16x16x32_bf16(af, bf2, ac2, 0, 0, 0);
    ac3 = __builtin_amdgcn_mfma_f32_16x16x32_bf16(af, bf3, ac3, 0, 0, 0);
  }

  // row-sum: reduce over the 4 lanes sharing l15 (lhi = 0..3)
  ssum += __shfl_xor(ssum, 16, 64);
  ssum += __shfl_xor(ssum, 32, 64);
  if (lane < 16) sums[w * 16 + l15] = ssum;

  // C partials: row = lhi*4+reg, col(feat) = ft*16+l15
#pragma unroll
  for (int reg = 0; reg < 4; ++reg) {
    int row = lhi * 4 + reg;
    float* dst = &red[w * 1088 + row * 68 + l15];
    dst[0] = ac0[reg];
    dst[16] = ac1[reg];
    dst[32] = ac2[reg];
    dst[48] = ac3[reg];
  }
  __syncthreads();

  // epilogue: 1024 outputs / 512 threads
#pragma unroll
  for (int rep = 0; rep < 2; ++rep) {
    int idx = t + rep * 512;
    int mm = idx >> 6, f = idx & 63;
    float v = 0.f, dn = 0.f;
#pragma unroll
    for (int w2 = 0; w2 < 8; ++w2) {
      v += red[w2 * 1088 + mm * 68 + f];
      dn += sums[w2 * 16 + mm];
    }
    float rdn = dn > 0.f ? 1.0f / dn : 0.f;
    float hp = v * rdn;
    float o = hp > 0.f ? hp : expm1f(hp);
    out[((size_t)b * NTOK + i0 + mm) * 64 + f] = o;
  }
}

extern "C" void kernel_launch(void* const* d_in, const int* in_sizes, int n_in,
                              void* d_out, int out_size, void* d_ws, size_t ws_size,
                              hipStream_t stream) {
  const float* h = (const float*)d_in[0];
  const int* adj = (const int*)d_in[1];
  const float* W = (const float*)d_in[2];
  const float* a = (const float*)d_in[3];
  float* out = (float*)d_out;

  unsigned short* WhT = (unsigned short*)d_ws;              // 2 MB
  float* f1 = (float*)((char*)d_ws + 2 * 1024 * 1024);      // 64 KB
  float* f2 = f1 + 16384;                                   // 64 KB
  unsigned* gmaxk = (unsigned*)(f2 + 16384);                // 32 B
  unsigned* gmink = gmaxk + 8;                              // 32 B

  gat_init<<<1, 64, 0, stream>>>(gmaxk, gmink);
  gat_pre<<<1024, 256, 0, stream>>>(h, W, a, WhT, f1, f2, gmaxk, gmink);
  gat_main<<<dim3(128, 8), 512, 0, stream>>>(adj, WhT, f1, f2, gmaxk, gmink, out);
}